// Round 1
// baseline (2244.248 us; speedup 1.0000x reference)
//
#include <hip/hip_runtime.h>

#define BB 4096
#define DD 512
#define NCC 5994

// ---------------------------------------------------------------------------
// Stage 1a: per-sample weight for the label-wise running average + label_add.
// cadd[l] = sum_j w_j x[i_j];  w_1 = 2^-(k-1), w_j = 2^-(k-j+1) (j>=2)
// rank0 = #occurrences of label[i] before i;  k = total count of label[i].
// ---------------------------------------------------------------------------
__global__ void ranks_kernel(const int* __restrict__ label, float* __restrict__ w,
                             float* __restrict__ label_add) {
    __shared__ int lab[BB];  // 16 KB
    int t = threadIdx.x;
    for (int j = t; j < BB; j += 256) lab[j] = label[j];
    __syncthreads();
    int i = blockIdx.x * 256 + t;   // grid is exactly BB threads
    int li = lab[i];
    int cnt = 0, rank = 0;
    for (int j = 0; j < BB; ++j) {
        int e = (lab[j] == li) ? 1 : 0;   // LDS broadcast read, conflict-free
        cnt += e;
        if (j < i) rank += e;
    }
    float expo = (rank == 0) ? (float)(cnt - 1) : (float)(cnt - rank);
    w[i] = exp2f(-expo);   // exact (small integer exponent)
    label_add[li] = 1.0f;  // benign race: all writers store 1.0
}

// ---------------------------------------------------------------------------
// Stage 1b: weighted scatter-add into cadd (zeroed by memset).
// ---------------------------------------------------------------------------
__global__ void cadd_kernel(const float* __restrict__ x, const int* __restrict__ label,
                            const float* __restrict__ w, float* __restrict__ cadd) {
    int i = blockIdx.x;
    int li = label[i];
    float wi = w[i];
    const float* xr = x + (size_t)i * DD;
    float* cr = cadd + (size_t)li * DD;
    int t = threadIdx.x;
    atomicAdd(&cr[t], wi * xr[t]);
    atomicAdd(&cr[t + 256], wi * xr[t + 256]);
}

// ---------------------------------------------------------------------------
// Stage 2: alpha = sigmoid(centers @ fc_w + fc_b); new_center blend.
// One block (256 thr) per class.
// ---------------------------------------------------------------------------
__global__ void newcenter_kernel(const float* __restrict__ centers,
                                 const float* __restrict__ fc_w,
                                 const float* __restrict__ fc_b,
                                 const float* __restrict__ cadd,
                                 const float* __restrict__ label_add,
                                 float* __restrict__ new_center) {
    int l = blockIdx.x;
    int t = threadIdx.x;
    const float* cr = centers + (size_t)l * DD;
    float part = fmaf(cr[t], fc_w[t], cr[t + 256] * fc_w[t + 256]);
#pragma unroll
    for (int off = 32; off; off >>= 1) part += __shfl_xor(part, off);
    __shared__ float wsum[4];
    if ((t & 63) == 0) wsum[t >> 6] = part;
    __syncthreads();
    float dot = wsum[0] + wsum[1] + wsum[2] + wsum[3] + fc_b[0];
    float alpha = 1.0f / (1.0f + expf(-dot));
    float la = label_add[l];
    float gate = alpha * la + (1.0f - la);
    float beta = (1.0f - alpha) * la;
    const float* car = cadd + (size_t)l * DD;
    float* nr = new_center + (size_t)l * DD;
    nr[t]       = fmaf(cr[t],       gate, car[t]       * beta);
    nr[t + 256] = fmaf(cr[t + 256], gate, car[t + 256] * beta);
}

// ---------------------------------------------------------------------------
// Stages 3/4: fused GEMM + cross-entropy (+ argmax/prec1 when HAS_LABELS).
// 8 rows per block staged in LDS; thread t handles classes t, t+256, ...
// Online (max, sumexp) + argmax in registers; wave shuffle-reduce; LDS merge.
// sums[0] += per-row CE, sums[1] += correct-count (HAS_LABELS only).
// ---------------------------------------------------------------------------
template <bool HAS_LABELS>
__global__ __launch_bounds__(256) void ce_kernel(
    const float* __restrict__ A, int nrows,
    const float* __restrict__ W, const float* __restrict__ bias,
    const int* __restrict__ labels, float* __restrict__ sums) {
    constexpr int ROWS = 8;
    __shared__ float4 xs[ROWS][DD / 4];  // 16 KB
    __shared__ float tgt[ROWS];
    __shared__ float rm[4][ROWS], rs[4][ROWS], rv[4][ROWS];
    __shared__ int ri[4][ROWS];

    int row0 = blockIdx.x * ROWS;
    int t = threadIdx.x;

    // stage the 8 A-rows (zeros for out-of-range rows)
    for (int idx = t; idx < ROWS * (DD / 4); idx += 256) {
        int r = idx >> 7;        // / 128
        int d4 = idx & 127;
        int row = row0 + r;
        float4 v = make_float4(0.f, 0.f, 0.f, 0.f);
        if (row < nrows) v = ((const float4*)A)[(size_t)row * (DD / 4) + d4];
        xs[r][d4] = v;
    }
    if (t < ROWS) tgt[t] = 0.f;
    __syncthreads();

    int target[ROWS];
#pragma unroll
    for (int r = 0; r < ROWS; ++r) {
        int row = row0 + r;
        if (HAS_LABELS) target[r] = (row < nrows) ? labels[row] : -1;
        else            target[r] = row;  // labels = arange(nClasses)
    }

    float m[ROWS], s[ROWS], amv[ROWS];
    int ami[ROWS];
#pragma unroll
    for (int r = 0; r < ROWS; ++r) { m[r] = -1e30f; s[r] = 0.f; amv[r] = -1e30f; ami[r] = 0x7fffffff; }

    for (int c = t; c < NCC; c += 256) {
        float acc[ROWS];
#pragma unroll
        for (int r = 0; r < ROWS; ++r) acc[r] = 0.f;
        const float4* wr = (const float4*)(W + (size_t)c * DD);
        for (int d4 = 0; d4 < DD / 4; ++d4) {
            float4 wv = wr[d4];
#pragma unroll
            for (int r = 0; r < ROWS; ++r) {
                float4 xv = xs[r][d4];  // same addr across lanes -> LDS broadcast
                acc[r] = fmaf(wv.x, xv.x, acc[r]);
                acc[r] = fmaf(wv.y, xv.y, acc[r]);
                acc[r] = fmaf(wv.z, xv.z, acc[r]);
                acc[r] = fmaf(wv.w, xv.w, acc[r]);
            }
        }
        float bc = bias[c];
#pragma unroll
        for (int r = 0; r < ROWS; ++r) {
            float lg = acc[r] + bc;
            float nm = fmaxf(m[r], lg);
            s[r] = fmaf(s[r], __expf(m[r] - nm), __expf(lg - nm));
            m[r] = nm;
            if (lg > amv[r]) { amv[r] = lg; ami[r] = c; }  // ascending c -> first max kept
            if (c == target[r]) tgt[r] = lg;               // single writer per row
        }
    }

    // wave-level butterfly merge of (m,s) and argmax
#pragma unroll
    for (int r = 0; r < ROWS; ++r) {
#pragma unroll
        for (int off = 32; off; off >>= 1) {
            float om = __shfl_xor(m[r], off);
            float os = __shfl_xor(s[r], off);
            float ov = __shfl_xor(amv[r], off);
            int   oi = __shfl_xor(ami[r], off);
            float nm = fmaxf(m[r], om);
            s[r] = fmaf(s[r], __expf(m[r] - nm), os * __expf(om - nm));
            m[r] = nm;
            if (ov > amv[r] || (ov == amv[r] && oi < ami[r])) { amv[r] = ov; ami[r] = oi; }
        }
    }
    int wave = t >> 6;
    if ((t & 63) == 0) {
#pragma unroll
        for (int r = 0; r < ROWS; ++r) {
            rm[wave][r] = m[r]; rs[wave][r] = s[r];
            rv[wave][r] = amv[r]; ri[wave][r] = ami[r];
        }
    }
    __syncthreads();

    if (t < ROWS) {
        int r = t, row = row0 + r;
        if (row < nrows) {
            float M = fmaxf(fmaxf(rm[0][r], rm[1][r]), fmaxf(rm[2][r], rm[3][r]));
            float S = rs[0][r] * __expf(rm[0][r] - M) + rs[1][r] * __expf(rm[1][r] - M)
                    + rs[2][r] * __expf(rm[2][r] - M) + rs[3][r] * __expf(rm[3][r] - M);
            float ce = -(tgt[r] - M - logf(S));
            atomicAdd(&sums[0], ce);
            if (HAS_LABELS) {
                float bv = rv[0][r]; int bi = ri[0][r];
#pragma unroll
                for (int wv = 1; wv < 4; ++wv)
                    if (rv[wv][r] > bv || (rv[wv][r] == bv && ri[wv][r] < bi)) { bv = rv[wv][r]; bi = ri[wv][r]; }
                if (bi == labels[row]) atomicAdd(&sums[1], 1.0f);
            }
        }
    }
}

// ---------------------------------------------------------------------------
// Stage 5: finalize the two scalars.
// sums layout: [0]=nloss_sum, [1]=correct_count, [2]=lossC_sum
// ---------------------------------------------------------------------------
__global__ void finalize_kernel(const float* __restrict__ sums, float* __restrict__ out) {
    out[0] = sums[0] / (float)BB + sums[2] / (float)NCC;
    out[1] = 100.0f * sums[1] / (float)BB;
}

extern "C" void kernel_launch(void* const* d_in, const int* in_sizes, int n_in,
                              void* d_out, int out_size, void* d_ws, size_t ws_size,
                              hipStream_t stream) {
    const float* x       = (const float*)d_in[0];
    const int*   label   = (const int*)d_in[1];
    const float* centers = (const float*)d_in[2];
    const float* fc_w    = (const float*)d_in[3];
    const float* fc_b    = (const float*)d_in[4];
    const float* ch_w    = (const float*)d_in[5];
    const float* ch_b    = (const float*)d_in[6];
    float* out = (float*)d_out;

    // workspace layout (floats): w[B] | label_add[NC] | cadd[NC*D] | new_center[NC*D] | sums[4]
    float* ws         = (float*)d_ws;
    float* w          = ws;
    float* label_add  = w + BB;
    float* cadd       = label_add + NCC;
    float* new_center = cadd + (size_t)NCC * DD;
    float* sums       = new_center + (size_t)NCC * DD;

    hipMemsetAsync(label_add, 0, NCC * sizeof(float), stream);
    hipMemsetAsync(cadd, 0, (size_t)NCC * DD * sizeof(float), stream);
    hipMemsetAsync(sums, 0, 4 * sizeof(float), stream);

    ranks_kernel<<<BB / 256, 256, 0, stream>>>(label, w, label_add);
    cadd_kernel<<<BB, 256, 0, stream>>>(x, label, w, cadd);
    newcenter_kernel<<<NCC, 256, 0, stream>>>(centers, fc_w, fc_b, cadd, label_add, new_center);

    ce_kernel<true><<<(BB + 7) / 8, 256, 0, stream>>>(x, BB, ch_w, ch_b, label, sums);
    ce_kernel<false><<<(NCC + 7) / 8, 256, 0, stream>>>(new_center, NCC, ch_w, ch_b, nullptr, sums + 2);

    finalize_kernel<<<1, 1, 0, stream>>>(sums, out);
}

// Round 3
// 362.404 us; speedup vs baseline: 6.1927x; 6.1927x over previous
//
#include <hip/hip_runtime.h>

#define BB 4096
#define DD 512
#define NCC 5994
#define NTT 24      // n-tiles of 256 cols (covers 6144 >= 5994)
#define XRB 64      // x row-blocks (4096/64)
#define CRB 94      // center row-blocks (ceil(5994/64))
#define NSL 3       // n-slices per row-block
#define TPS 8       // tiles per slice (24/3)
#define PSZ 30272   // partial-array stride (>= 4096*3 + 5994*3 = 30270)

typedef __attribute__((ext_vector_type(8))) short bfx8;
typedef __attribute__((ext_vector_type(8))) unsigned short usx8;
typedef __attribute__((ext_vector_type(4))) float fx4;

__device__ __forceinline__ unsigned short f2bf(float f) {
    unsigned u = __builtin_bit_cast(unsigned, f);
    u += 0x7fff + ((u >> 16) & 1);   // RNE
    return (unsigned short)(u >> 16);
}

__device__ __forceinline__ void gload_lds16(const void* g, void* l) {
    __builtin_amdgcn_global_load_lds(
        (const __attribute__((address_space(1))) void*)g,
        (__attribute__((address_space(3))) void*)l, 16, 0, 0);
}

// ---------------------------------------------------------------------------
// Stage 1a: per-sample weight for label-wise running average + label_add.
// ---------------------------------------------------------------------------
__global__ void ranks_kernel(const int* __restrict__ label, float* __restrict__ w,
                             float* __restrict__ label_add) {
    __shared__ int lab[BB];
    int t = threadIdx.x;
    for (int j = t; j < BB; j += 256) lab[j] = label[j];
    __syncthreads();
    int i = blockIdx.x * 256 + t;
    int li = lab[i];
    int cnt = 0, rank = 0;
    for (int j = 0; j < BB; ++j) {
        int e = (lab[j] == li) ? 1 : 0;
        cnt += e;
        if (j < i) rank += e;
    }
    float expo = (rank == 0) ? (float)(cnt - 1) : (float)(cnt - rank);
    w[i] = exp2f(-expo);
    label_add[li] = 1.0f;
}

// ---------------------------------------------------------------------------
// Stage 1b: weighted scatter-add into cadd (zeroed by memset).
// ---------------------------------------------------------------------------
__global__ void cadd_kernel(const float* __restrict__ x, const int* __restrict__ label,
                            const float* __restrict__ w, float* __restrict__ cadd) {
    int i = blockIdx.x;
    int li = label[i];
    float wi = w[i];
    const float* xr = x + (size_t)i * DD;
    float* cr = cadd + (size_t)li * DD;
    int t = threadIdx.x;
    atomicAdd(&cr[t], wi * xr[t]);
    atomicAdd(&cr[t + 256], wi * xr[t + 256]);
}

// ---------------------------------------------------------------------------
// Stage 2: alpha = sigmoid(centers @ fc_w + fc_b); new_center blend.
// ---------------------------------------------------------------------------
__global__ void newcenter_kernel(const float* __restrict__ centers,
                                 const float* __restrict__ fc_w,
                                 const float* __restrict__ fc_b,
                                 const float* __restrict__ cadd,
                                 const float* __restrict__ label_add,
                                 float* __restrict__ new_center) {
    int l = blockIdx.x;
    int t = threadIdx.x;
    const float* cr = centers + (size_t)l * DD;
    float part = fmaf(cr[t], fc_w[t], cr[t + 256] * fc_w[t + 256]);
#pragma unroll
    for (int off = 32; off; off >>= 1) part += __shfl_xor(part, off);
    __shared__ float wsum[4];
    if ((t & 63) == 0) wsum[t >> 6] = part;
    __syncthreads();
    float dot = wsum[0] + wsum[1] + wsum[2] + wsum[3] + fc_b[0];
    float alpha = 1.0f / (1.0f + expf(-dot));
    float la = label_add[l];
    float gate = alpha * la + (1.0f - la);
    float beta = (1.0f - alpha) * la;
    const float* car = cadd + (size_t)l * DD;
    float* nr = new_center + (size_t)l * DD;
    nr[t]       = fmaf(cr[t],       gate, car[t]       * beta);
    nr[t + 256] = fmaf(cr[t + 256], gate, car[t + 256] * beta);
}

// ---------------------------------------------------------------------------
// ch_w fp32 -> bf16
// ---------------------------------------------------------------------------
__global__ void wconv_kernel(const float* __restrict__ src, unsigned short* __restrict__ dst) {
    int i = blockIdx.x * 256 + threadIdx.x;
    if (i * 8 >= NCC * DD) return;
    const float4* g = (const float4*)(src + (size_t)i * 8);
    float4 v0 = g[0], v1 = g[1];
    usx8 u;
    u[0] = f2bf(v0.x); u[1] = f2bf(v0.y); u[2] = f2bf(v0.z); u[3] = f2bf(v0.w);
    u[4] = f2bf(v1.x); u[5] = f2bf(v1.y); u[6] = f2bf(v1.z); u[7] = f2bf(v1.w);
    *(usx8*)(dst + (size_t)i * 8) = u;
}

// ---------------------------------------------------------------------------
// Fused MFMA GEMM + online softmax/CE partials.
// Blocks 0..191: x-mode (rb = b%64, slice = b/64)
// Blocks 192..473: center-mode (rb = c%94, slice = c/94)
// Each block: 64 rows x (8 n-tiles of 256 cols), K=512.
// A-tile LDS-resident (bf16, XOR-swizzled); W chunks [256][64] double-buffered
// via global_load_lds with pre-swizzled global source (linear LDS dest).
// ---------------------------------------------------------------------------
__global__ __launch_bounds__(512, 2) void mfma_ce_kernel(
    const float* __restrict__ xg, const float* __restrict__ ncg,
    const unsigned short* __restrict__ wb, const float* __restrict__ chb,
    const int* __restrict__ labelg,
    float* __restrict__ pm, float* __restrict__ ps, float* __restrict__ pt,
    float* __restrict__ pv, int* __restrict__ pi)
{
    __shared__ short lA[64 * 512];       // 64 KB
    __shared__ short lB[2][256 * 64];    // 64 KB

    int b = blockIdx.x;
    int xm, rb, slice, nrows;
    const float* src;
    if (b < XRB * NSL) { xm = 1; rb = b % XRB; slice = b / XRB; nrows = BB;  src = xg; }
    else { int c = b - XRB * NSL; xm = 0; rb = c % CRB; slice = c / CRB; nrows = NCC; src = ncg; }
    int row0  = rb * 64;
    int tile0 = slice * TPS;

    int t = threadIdx.x;
    char* lAc = (char*)lA;

    // ---- stage A tile: fp32 -> bf16, swizzled writes ----
#pragma unroll
    for (int i = 0; i < 8; ++i) {
        int c = t + i * 512;            // chunk 0..4095 (64 rows x 64 slots of 8 elems)
        int r = c >> 6, s8 = c & 63;
        float4 v0 = make_float4(0.f, 0.f, 0.f, 0.f), v1 = v0;
        if (row0 + r < nrows) {
            const float4* g = (const float4*)(src + (size_t)(row0 + r) * DD + s8 * 8);
            v0 = g[0]; v1 = g[1];
        }
        usx8 u;
        u[0] = f2bf(v0.x); u[1] = f2bf(v0.y); u[2] = f2bf(v0.z); u[3] = f2bf(v0.w);
        u[4] = f2bf(v1.x); u[5] = f2bf(v1.y); u[6] = f2bf(v1.z); u[7] = f2bf(v1.w);
        int byte = r * 1024 + ((s8 * 16) ^ ((r & 7) << 4));
        *(usx8*)(lAc + byte) = u;
    }

    int lane = t & 63, wv = t >> 6;
    int wm = wv >> 2, wn = wv & 3;
    int l15 = lane & 15, l4 = lane >> 4;

    // W DMA geometry: per wave-instr, 8 rows x 8 slots; dest linear, source pre-swizzled.
    int drow_base = wv * 32;
    int dr_lane = lane >> 3, dslot = lane & 7;

    auto issueW = [&](int stepIdx, int bufIdx) {
        int tt = tile0 + (stepIdx >> 3);
        int kc = stepIdx & 7;
#pragma unroll
        for (int q = 0; q < 4; ++q) {
            int rit = drow_base + q * 8 + dr_lane;     // row in tile 0..255
            int cls = tt * 256 + rit;
            cls = min(cls, NCC - 1);                   // clamp OOB classes (masked later)
            int sslot = dslot ^ (rit & 7);
            const unsigned short* gp = wb + (size_t)cls * DD + kc * 64 + sslot * 8;
            short* lp = &lB[bufIdx][(drow_base + q * 8) * 64];
            gload_lds16(gp, lp);
        }
    };

    // A fragment addressing (mf offsets are multiples of 16 so swizzle bits constant)
    int rowA0  = wm * 32 + l15;
    int abase0 = rowA0 * 1024;
    int abase1 = (rowA0 + 16) * 1024;
    int aswz   = (rowA0 & 7) << 4;
    // B fragment addressing
    int crow0 = wn * 64 + l15;
    int bswz  = (crow0 & 7) << 4;

    // softmax state per (mf, j): row = row0 + wm*32 + mf*16 + l4*4 + j
    float m_[2][4], s_[2][4], tg_[2][4], av_[2][4];
    int ai_[2][4], tc_[2][4];
#pragma unroll
    for (int mf = 0; mf < 2; ++mf)
#pragma unroll
        for (int j = 0; j < 4; ++j) {
            m_[mf][j] = -1e30f; s_[mf][j] = 0.f; tg_[mf][j] = 0.f;
            av_[mf][j] = -1e30f; ai_[mf][j] = 0x7fffffff;
            int grow = row0 + wm * 32 + mf * 16 + l4 * 4 + j;
            int tcv;
            if (xm) tcv = labelg[min(grow, BB - 1)];
            else    tcv = grow;
            if (grow >= nrows) tcv = -1;
            tc_[mf][j] = tcv;
        }

    issueW(0, 0);
    __syncthreads();

    int buf = 0;
    fx4 acc[2][4];
    float biasv[4];

    for (int step = 0; step < 64; ++step) {   // 8 tiles x 8 k-chunks
        int kc = step & 7;
        int tt = tile0 + (step >> 3);
        if (step + 1 < 64) issueW(step + 1, buf ^ 1);
        if (kc == 0) {
#pragma unroll
            for (int mf = 0; mf < 2; ++mf)
#pragma unroll
                for (int nf = 0; nf < 4; ++nf) {
                    fx4 z = {0.f, 0.f, 0.f, 0.f};
                    acc[mf][nf] = z;
                }
#pragma unroll
            for (int nf = 0; nf < 4; ++nf) {
                int col = tt * 256 + wn * 64 + nf * 16 + l15;
                biasv[nf] = (col < NCC) ? chb[col] : 0.f;
            }
        }
        const char* lBc = (const char*)lB[buf];
#pragma unroll
        for (int ks = 0; ks < 2; ++ks) {
            int ka = kc * 128 + ks * 64 + l4 * 16;
            bfx8 a0 = *(const bfx8*)(lAc + abase0 + (ka ^ aswz));
            bfx8 a1 = *(const bfx8*)(lAc + abase1 + (ka ^ aswz));
            int kb = (ks * 64 + l4 * 16) ^ bswz;
            bfx8 b0 = *(const bfx8*)(lBc + (crow0     ) * 128 + kb);
            bfx8 b1 = *(const bfx8*)(lBc + (crow0 + 16) * 128 + kb);
            bfx8 b2 = *(const bfx8*)(lBc + (crow0 + 32) * 128 + kb);
            bfx8 b3 = *(const bfx8*)(lBc + (crow0 + 48) * 128 + kb);
            acc[0][0] = __builtin_amdgcn_mfma_f32_16x16x32_bf16(a0, b0, acc[0][0], 0, 0, 0);
            acc[0][1] = __builtin_amdgcn_mfma_f32_16x16x32_bf16(a0, b1, acc[0][1], 0, 0, 0);
            acc[0][2] = __builtin_amdgcn_mfma_f32_16x16x32_bf16(a0, b2, acc[0][2], 0, 0, 0);
            acc[0][3] = __builtin_amdgcn_mfma_f32_16x16x32_bf16(a0, b3, acc[0][3], 0, 0, 0);
            acc[1][0] = __builtin_amdgcn_mfma_f32_16x16x32_bf16(a1, b0, acc[1][0], 0, 0, 0);
            acc[1][1] = __builtin_amdgcn_mfma_f32_16x16x32_bf16(a1, b1, acc[1][1], 0, 0, 0);
            acc[1][2] = __builtin_amdgcn_mfma_f32_16x16x32_bf16(a1, b2, acc[1][2], 0, 0, 0);
            acc[1][3] = __builtin_amdgcn_mfma_f32_16x16x32_bf16(a1, b3, acc[1][3], 0, 0, 0);
        }
        if (kc == 7) {
            // epilogue: online softmax update for tile tt
#pragma unroll
            for (int nf = 0; nf < 4; ++nf) {
                int col = tt * 256 + wn * 64 + nf * 16 + l15;
                bool cv = col < NCC;
#pragma unroll
                for (int mf = 0; mf < 2; ++mf)
#pragma unroll
                    for (int j = 0; j < 4; ++j) {
                        if (cv) {
                            float v = acc[mf][nf][j] + biasv[nf];
                            float nm = fmaxf(m_[mf][j], v);
                            s_[mf][j] = s_[mf][j] * __expf(m_[mf][j] - nm) + __expf(v - nm);
                            m_[mf][j] = nm;
                            if (xm && v > av_[mf][j]) { av_[mf][j] = v; ai_[mf][j] = col; }
                            if (col == tc_[mf][j]) tg_[mf][j] = v;
                        }
                    }
            }
        }
        __syncthreads();
        buf ^= 1;
    }

    // intra-wave merge across the 16-lane col group
#pragma unroll
    for (int off = 1; off < 16; off <<= 1) {
#pragma unroll
        for (int mf = 0; mf < 2; ++mf)
#pragma unroll
            for (int j = 0; j < 4; ++j) {
                float om = __shfl_xor(m_[mf][j], off);
                float os = __shfl_xor(s_[mf][j], off);
                float ot = __shfl_xor(tg_[mf][j], off);
                float ov = __shfl_xor(av_[mf][j], off);
                int   oi = __shfl_xor(ai_[mf][j], off);
                float nm = fmaxf(m_[mf][j], om);
                s_[mf][j] = s_[mf][j] * __expf(m_[mf][j] - nm) + os * __expf(om - nm);
                m_[mf][j] = nm;
                tg_[mf][j] += ot;
                if (ov > av_[mf][j] || (ov == av_[mf][j] && oi < ai_[mf][j])) {
                    av_[mf][j] = ov; ai_[mf][j] = oi;
                }
            }
    }

    // cross-wave merge via LDS (reuse lB; all reads of it completed before last barrier)
    float* red = (float*)lB;           // [4 arrays][4 wn][64 rows] + int array
    int* redi = (int*)(red + 4 * 256);
    if (l15 == 0) {
#pragma unroll
        for (int mf = 0; mf < 2; ++mf)
#pragma unroll
            for (int j = 0; j < 4; ++j) {
                int rowloc = wm * 32 + mf * 16 + l4 * 4 + j;
                int idx = wn * 64 + rowloc;
                red[0 * 256 + idx] = m_[mf][j];
                red[1 * 256 + idx] = s_[mf][j];
                red[2 * 256 + idx] = tg_[mf][j];
                red[3 * 256 + idx] = av_[mf][j];
                redi[idx]          = ai_[mf][j];
            }
    }
    __syncthreads();
    if (t < 64) {
        int grow = row0 + t;
        if (grow < nrows) {
            float M = -1e30f, S = 0.f, T = 0.f, V = -1e30f; int I = 0x7fffffff;
#pragma unroll
            for (int wn2 = 0; wn2 < 4; ++wn2) {
                int idx = wn2 * 64 + t;
                float m2 = red[idx], s2 = red[256 + idx];
                float nm = fmaxf(M, m2);
                S = S * __expf(M - nm) + s2 * __expf(m2 - nm); M = nm;
                T += red[512 + idx];
                float v2 = red[768 + idx]; int i2 = redi[idx];
                if (v2 > V || (v2 == V && i2 < I)) { V = v2; I = i2; }
            }
            int pidx = xm ? (grow * NSL + slice) : (BB * NSL + grow * NSL + slice);
            pm[pidx] = M; ps[pidx] = S; pt[pidx] = T; pv[pidx] = V; pi[pidx] = I;
        }
    }
}

// ---------------------------------------------------------------------------
// Merge partials per row -> CE / prec1 accumulators.
// ---------------------------------------------------------------------------
__global__ void merge_kernel(const float* __restrict__ pm, const float* __restrict__ ps,
                             const float* __restrict__ pt, const float* __restrict__ pv,
                             const int* __restrict__ pi, const int* __restrict__ label,
                             float* __restrict__ sums) {
    int tid = blockIdx.x * 256 + threadIdx.x;
    float ce = 0.f, corr = 0.f;
    int isx = (tid < BB) ? 1 : 0;
    int base = -1;
    if (tid < BB) base = tid * NSL;
    else if (tid < BB + NCC) base = BB * NSL + (tid - BB) * NSL;
    if (base >= 0) {
        float M = -1e30f, S = 0.f, T = 0.f, V = -1e30f; int I = 0x7fffffff;
#pragma unroll
        for (int s2 = 0; s2 < NSL; ++s2) {
            float m = pm[base + s2], s = ps[base + s2];
            float nm = fmaxf(M, m);
            S = S * __expf(M - nm) + s * __expf(m - nm); M = nm;
            T += pt[base + s2];
            float v = pv[base + s2]; int i2 = pi[base + s2];
            if (v > V || (v == V && i2 < I)) { V = v; I = i2; }
        }
        ce = -(T - M - logf(S));
        if (isx) corr = (I == label[tid]) ? 1.f : 0.f;
    }
#pragma unroll
    for (int off = 32; off; off >>= 1) {
        ce += __shfl_xor(ce, off);
        corr += __shfl_xor(corr, off);
    }
    if ((threadIdx.x & 63) == 0) {
        atomicAdd(&sums[isx ? 0 : 2], ce);
        if (isx) atomicAdd(&sums[1], corr);
    }
}

__global__ void finalize_kernel(const float* __restrict__ sums, float* __restrict__ out) {
    out[0] = sums[0] / (float)BB + sums[2] / (float)NCC;
    out[1] = 100.0f * sums[1] / (float)BB;
}

extern "C" void kernel_launch(void* const* d_in, const int* in_sizes, int n_in,
                              void* d_out, int out_size, void* d_ws, size_t ws_size,
                              hipStream_t stream) {
    const float* x       = (const float*)d_in[0];
    const int*   label   = (const int*)d_in[1];
    const float* centers = (const float*)d_in[2];
    const float* fc_w    = (const float*)d_in[3];
    const float* fc_b    = (const float*)d_in[4];
    const float* ch_w    = (const float*)d_in[5];
    const float* ch_b    = (const float*)d_in[6];
    float* out = (float*)d_out;

    // ws layout (floats):
    // [0,4096) w | [4096,10090) label_add | [10090,10094) sums | pad |
    // [10096, +NCC*DD) new_center | [3079024, +NCC*DD) cadd (later overlaid by
    //   wb (bf16 ch_w, 1534464 floats) + partial arrays 5*PSZ)
    float* ws         = (float*)d_ws;
    float* w          = ws;
    float* label_add  = ws + 4096;
    float* sums       = ws + 10090;
    float* new_center = ws + 10096;
    float* cadd       = ws + 10096 + (size_t)NCC * DD;
    unsigned short* wb = (unsigned short*)cadd;
    float* pm = cadd + 1534464;
    float* ps = pm + PSZ;
    float* pt = ps + PSZ;
    float* pv = pt + PSZ;
    int*   pi = (int*)(pv + PSZ);

    hipMemsetAsync(label_add, 0, NCC * sizeof(float), stream);
    hipMemsetAsync(cadd, 0, (size_t)NCC * DD * sizeof(float), stream);
    hipMemsetAsync(sums, 0, 4 * sizeof(float), stream);

    ranks_kernel<<<BB / 256, 256, 0, stream>>>(label, w, label_add);
    cadd_kernel<<<BB, 256, 0, stream>>>(x, label, w, cadd);
    newcenter_kernel<<<NCC, 256, 0, stream>>>(centers, fc_w, fc_b, cadd, label_add, new_center);
    // cadd fully consumed; overlay region now safe to overwrite
    wconv_kernel<<<(NCC * DD / 8 + 255) / 256, 256, 0, stream>>>(ch_w, wb);

    mfma_ce_kernel<<<XRB * NSL + CRB * NSL, 512, 0, stream>>>(
        x, new_center, wb, ch_b, label, pm, ps, pt, pv, pi);

    merge_kernel<<<(BB + NCC + 255) / 256, 256, 0, stream>>>(pm, ps, pt, pv, pi, label, sums);
    finalize_kernel<<<1, 1, 0, stream>>>(sums, out);
}